// Round 9
// baseline (89.804 us; speedup 1.0000x reference)
//
#include <hip/hip_runtime.h>

// Performer causal linear attention (generalized relu kernel), fp32 in/out.
// B=1, H=8, N=1024, D=64, M=128. Chunked formulation, chunk C=128:
//   qp = relu(norm * q @ proj^T) + eps ; kp likewise
//   Z  = cumsum_n kp ; W = qp / Z
//   out_c = W_c @ S0_c + tril(W_c @ Kp_c^T) @ V_c ; S0_c = prefix of Kp^T V
// R9: coalescing fixes. K1: q+k merged per block (proj staged once; 256
// blocks x 512 thr), all epilogues via LDS -> ushort4 coalesced stores
// (replaces 48 scalar 2B stores/thread). K2: own-chunk qp staged to LDS;
// z-scan sources kp/qp from LDS (replaces 64 uncoalesced ushort loads).
static constexpr int H = 8, N = 1024, D = 64, M = 128, CHUNK = 128, NC = 8;
static constexpr float EPS = 1e-3f;
static constexpr float NORM = 0.35355339059327373f; // 64^-0.25

typedef __attribute__((ext_vector_type(8))) short short8;
typedef __attribute__((ext_vector_type(4))) float f32x4;

__device__ inline unsigned short f2bf(float x) {
    unsigned u = __float_as_uint(x);
    return (unsigned short)((u + 0x7fffu + ((u >> 16) & 1u)) >> 16);
}
__device__ inline float bf2f(unsigned short u) {
    return __uint_as_float(((unsigned)u) << 16);
}
__device__ inline ushort4 pack4(float4 g) {
    return (ushort4){f2bf(g.x), f2bf(g.y), f2bf(g.z), f2bf(g.w)};
}

// -------- K1: qpb/kpb = bf16(relu(norm x @ proj^T)+eps), Gpb, kpart.
// grid (32 rblk, 8 h), 512 thr. One block: 32 rows of BOTH q and k.
__global__ __launch_bounds__(512) void k_projg(const float* __restrict__ q,
                                               const float* __restrict__ k,
                                               const float* __restrict__ proj,
                                               const float* __restrict__ v,
                                               unsigned short* __restrict__ qpb,
                                               unsigned short* __restrict__ kpb,
                                               unsigned short* __restrict__ Gpb,
                                               float* __restrict__ kpart) {
    __shared__ __align__(16) short smem[30208]; // 60.4 KB
    short* projb = smem;         // [m 128][72] B-operand
    short* xb = smem + 9216;     // [r 64][72] A-operand (q rows 0-31, k 32-63)
    short* obuf = smem + 13824;  // [64][136] out tile / later [128][68] G
    short* kpT = smem + 22528;   // [m 128][40] A-operand for G
    short* vT = smem + 27648;    // [e 64][40] B-operand for G
    const int tid = threadIdx.x;
    const int rblk = blockIdx.x;
    const int h = blockIdx.y;
    const int rowbase = h * N + rblk * 32;
    const int lane = tid & 63, wv = tid >> 6;
    const int rt = wv & 3, mh = wv >> 2;
    const int fr = lane & 15, fq = lane >> 4;

    // ---- stage proj (4 float4/thread), q, k (1 each), v^T (1 each)
    for (int i4 = tid; i4 < 2048; i4 += 512) {
        int m = i4 >> 4, dq = i4 & 15;
        *(ushort4*)&projb[m * 72 + dq * 4] = pack4(*(const float4*)&proj[i4 * 4]);
    }
    {
        int r = tid >> 4, dq = tid & 15;
        float4 g = *(const float4*)&q[(rowbase + r) * D + dq * 4];
        g.x *= NORM; g.y *= NORM; g.z *= NORM; g.w *= NORM;
        *(ushort4*)&xb[r * 72 + dq * 4] = pack4(g);
        float4 gk = *(const float4*)&k[(rowbase + r) * D + dq * 4];
        gk.x *= NORM; gk.y *= NORM; gk.z *= NORM; gk.w *= NORM;
        *(ushort4*)&xb[(32 + r) * 72 + dq * 4] = pack4(gk);
        int rv = tid & 31, e4 = (tid >> 5) * 4;
        float4 gv = *(const float4*)&v[(rowbase + rv) * D + e4];
        vT[(e4 + 0) * 40 + rv] = (short)f2bf(gv.x);
        vT[(e4 + 1) * 40 + rv] = (short)f2bf(gv.y);
        vT[(e4 + 2) * 40 + rv] = (short)f2bf(gv.z);
        vT[(e4 + 3) * 40 + rv] = (short)f2bf(gv.w);
    }
    __syncthreads();

    // ---- GEMM: 64 rows x 128 m, K=64. Wave (rt, mh): 4 m-tiles x 2 kt.
    f32x4 accp[4];
#pragma unroll
    for (int i = 0; i < 4; i++) accp[i] = (f32x4){0.f, 0.f, 0.f, 0.f};
#pragma unroll
    for (int kt = 0; kt < 2; kt++) {
        short8 a = *(const short8*)&xb[(16 * rt + fr) * 72 + kt * 32 + fq * 8];
#pragma unroll
        for (int i = 0; i < 4; i++) {
            const int mt = mh * 4 + i;
            short8 bb = *(const short8*)&projb[(16 * mt + fr) * 72 + kt * 32 + fq * 8];
            accp[i] = __builtin_amdgcn_mfma_f32_16x16x32_bf16(a, bb, accp[i], 0, 0, 0);
        }
    }
    // epilogue -> obuf[r][136] (+ kpT for k rows)
#pragma unroll
    for (int i = 0; i < 4; i++) {
        const int mt = mh * 4 + i;
#pragma unroll
        for (int reg = 0; reg < 4; reg++) {
            const int r = 16 * rt + fq * 4 + reg; // 0..63
            const int m = 16 * mt + fr;
            unsigned short bv = f2bf(fmaxf(accp[i][reg], 0.f) + EPS);
            obuf[r * 136 + m] = (short)bv;
            if (rt >= 2) kpT[m * 40 + (r - 32)] = (short)bv;
        }
    }
    __syncthreads();

    // ---- coalesced qpb/kpb stores (4 x 8B per thread); kpart
    for (int i = tid; i < 2048; i += 512) {
        int r = i >> 5, cu = i & 31;
        ushort4 val = *(const ushort4*)&obuf[r * 136 + cu * 4];
        unsigned short* g = (r < 32) ? &qpb[(rowbase + r) * M + cu * 4]
                                     : &kpb[(rowbase + r - 32) * M + cu * 4];
        *(ushort4*)g = val;
    }
    const int gb = h * 32 + rblk;
    if (tid < 128) {
        float ks = 0.f;
#pragma unroll 8
        for (int r = 0; r < 32; r++) ks += bf2f((unsigned short)kpT[tid * 40 + r]);
        kpart[gb * M + tid] = ks;
    }
    __syncthreads(); // obuf reads done

    // ---- G = Kp^T V (128m x 64e, K=32). Wave w: m-tile w, 4 e-tiles.
    f32x4 gacc[4];
#pragma unroll
    for (int et = 0; et < 4; et++) gacc[et] = (f32x4){0.f, 0.f, 0.f, 0.f};
    {
        short8 a = *(const short8*)&kpT[(16 * wv + fr) * 40 + fq * 8];
#pragma unroll
        for (int et = 0; et < 4; et++) {
            short8 bb = *(const short8*)&vT[(16 * et + fr) * 40 + fq * 8];
            gacc[et] = __builtin_amdgcn_mfma_f32_16x16x32_bf16(a, bb, gacc[et], 0, 0, 0);
        }
    }
#pragma unroll
    for (int et = 0; et < 4; et++)
#pragma unroll
        for (int reg = 0; reg < 4; reg++) {
            const int m = 16 * wv + fq * 4 + reg;
            obuf[m * 68 + 16 * et + fr] = (short)f2bf(gacc[et][reg]);
        }
    __syncthreads();
    // coalesced Gpb stores (4 x 8B per thread)
    for (int i = tid; i < 2048; i += 512) {
        int m = i >> 4, e4 = (i & 15) * 4;
        *(ushort4*)&Gpb[(gb * M + m) * D + e4] = *(const ushort4*)&obuf[m * 68 + e4];
    }
}

// -------- K2: grid (64, 4 subs), 512 thr. Per block: 32 output rows.
__global__ __launch_bounds__(512) void k_attn(const unsigned short* __restrict__ qpb,
                                              const unsigned short* __restrict__ kpb,
                                              const float* __restrict__ kpart,
                                              const unsigned short* __restrict__ Gpb,
                                              const float* __restrict__ v,
                                              float* __restrict__ out) {
    __shared__ __align__(16) short smem[26112]; // 52.2 KB
    short* bufA = smem;          // W  [32][136]
    short* bufB = smem + 4352;   // Kp [128][136]; later S0T/VT [64][136]
    short* bufC = smem + 21760;  // qp staging [32][136]; later Pb [32][136]
    const int tid = threadIdx.x;
    const int b = blockIdx.x;
    const int sub = blockIdx.y;
    const int h = b >> 3, c = 7 - (b & 7); // heavy chunks first
    const int chunkbase = h * N + c * CHUNK;
    const int rowstart = chunkbase + sub * 32;
    const int lane = tid & 63, wv = tid >> 6;
    const int rt = wv & 1, js = wv >> 1;
    const int fr = lane & 15, fq = lane >> 4;

    // ---- stage Kp chunk (128x128) and own qp rows (32x128), coalesced
    {
        const unsigned int* src = (const unsigned int*)kpb;
        for (int i = tid; i < 8192; i += 512) {
            int j = i >> 6, mu = i & 63;
            ((unsigned int*)&bufB[j * 136])[mu] = src[(chunkbase + j) * 64 + mu];
        }
        const unsigned int* srcq = (const unsigned int*)qpb;
        for (int i = tid; i < 2048; i += 512) {
            int r = i >> 6, mu = i & 63;
            ((unsigned int*)&bufC[r * 136])[mu] = srcq[(rowstart + r) * 64 + mu];
        }
    }
    __syncthreads();

    // ---- z-scan (tid<128, LDS-sourced) + S0 chunk-prefix regs (all)
    if (tid < 128) {
        const int m = tid;
        float z = 0.f;
        const int send = c * 4 + sub;
        for (int s = 0; s < send; s++) z += kpart[(h * 32 + s) * M + m];
#pragma unroll 8
        for (int r = 0; r < 32; r++) {
            z += bf2f((unsigned short)bufB[(sub * 32 + r) * 136 + m]);
            bufA[r * 136 + m] = (short)f2bf(
                bf2f((unsigned short)bufC[r * 136 + m]) * __builtin_amdgcn_rcpf(z));
        }
    }
    float s0r[16];
#pragma unroll
    for (int j = 0; j < 16; j++) s0r[j] = 0.f;
    for (int cp = 0; cp < c; cp++) {
#pragma unroll
        for (int p = 0; p < 4; p++) {
            const short* gsrc =
                (const short*)&Gpb[(h * 32 + cp * 4 + p) * (M * D) + tid * 16];
            short8 g0 = *(const short8*)&gsrc[0];
            short8 g1 = *(const short8*)&gsrc[8];
#pragma unroll
            for (int j = 0; j < 8; j++) {
                s0r[j] += bf2f((unsigned short)g0[j]);
                s0r[8 + j] += bf2f((unsigned short)g1[j]);
            }
        }
    }
    __syncthreads();

    // ---- P1: A = tril(W @ Kp^T), rows 32, cols up to (sub+1)*32
    const int jtmax = 2 * sub + 2;
    f32x4 acc1[2];
    acc1[0] = (f32x4){0.f, 0.f, 0.f, 0.f};
    acc1[1] = (f32x4){0.f, 0.f, 0.f, 0.f};
#pragma unroll
    for (int kt = 0; kt < 4; kt++) {
        short8 a = *(const short8*)&bufA[(16 * rt + fr) * 136 + kt * 32 + fq * 8];
#pragma unroll
        for (int jl = 0; jl < 2; jl++) {
            const int jt = 2 * js + jl;
            if (jt < jtmax) {
                short8 bb =
                    *(const short8*)&bufB[(16 * jt + fr) * 136 + kt * 32 + fq * 8];
                acc1[jl] =
                    __builtin_amdgcn_mfma_f32_16x16x32_bf16(a, bb, acc1[jl], 0, 0, 0);
            }
        }
    }
    __syncthreads(); // qp reads (zscan) long done; ensure bufC free & Kp read done
    // mask + C/D -> A-operand relayout into bufC (Pb)
#pragma unroll
    for (int jl = 0; jl < 2; jl++) {
        const int jt = 2 * js + jl;
        if (jt < jtmax) {
            const int j = 16 * jt + fr;
#pragma unroll
            for (int reg = 0; reg < 4; reg++) {
                const int nloc = 16 * rt + fq * 4 + reg;
                float val = (j <= sub * 32 + nloc) ? acc1[jl][reg] : 0.f;
                bufC[nloc * 136 + j] = (short)f2bf(val);
            }
        }
    }

    // ---- stage S0^T from regs: bufB[e][136] = S0[m][e]
    {
        const int m = tid >> 2;
        const int ebase = (tid & 3) * 16;
#pragma unroll
        for (int j = 0; j < 16; j++)
            bufB[(ebase + j) * 136 + m] = (short)f2bf(s0r[j]);
    }
    __syncthreads();

    // ---- P2a: out = W @ S0 (K=128); wave (rt, et=js)
    f32x4 acc2 = (f32x4){0.f, 0.f, 0.f, 0.f};
#pragma unroll
    for (int kt = 0; kt < 4; kt++) {
        short8 a = *(const short8*)&bufA[(16 * rt + fr) * 136 + kt * 32 + fq * 8];
        short8 bb = *(const short8*)&bufB[(16 * js + fr) * 136 + kt * 32 + fq * 8];
        acc2 = __builtin_amdgcn_mfma_f32_16x16x32_bf16(a, bb, acc2, 0, 0, 0);
    }
    __syncthreads(); // S0T reads done

    // ---- stage V^T: bufB[e][136] = v[j][e]
    for (int i = tid; i < 2048; i += 512) {
        int j = i >> 4, e4 = (i & 15) * 4;
        float4 g = *(const float4*)&v[(chunkbase + j) * D + e4];
        bufB[(e4 + 0) * 136 + j] = (short)f2bf(g.x);
        bufB[(e4 + 1) * 136 + j] = (short)f2bf(g.y);
        bufB[(e4 + 2) * 136 + j] = (short)f2bf(g.z);
        bufB[(e4 + 3) * 136 + j] = (short)f2bf(g.w);
    }
    __syncthreads();

    // ---- P2b: out += P @ V (K limited to (sub+1)*32 by causality)
    const int ktmax = sub + 1;
    for (int kt = 0; kt < ktmax; kt++) {
        short8 a = *(const short8*)&bufC[(16 * rt + fr) * 136 + kt * 32 + fq * 8];
        short8 bb = *(const short8*)&bufB[(16 * js + fr) * 136 + kt * 32 + fq * 8];
        acc2 = __builtin_amdgcn_mfma_f32_16x16x32_bf16(a, bb, acc2, 0, 0, 0);
    }

    // ---- epilogue
#pragma unroll
    for (int reg = 0; reg < 4; reg++) {
        out[(rowstart + 16 * rt + fq * 4 + reg) * D + 16 * js + fr] = acc2[reg];
    }
}

extern "C" void kernel_launch(void* const* d_in, const int* in_sizes, int n_in,
                              void* d_out, int out_size, void* d_ws, size_t ws_size,
                              hipStream_t stream) {
    const float* q = (const float*)d_in[0];
    const float* k = (const float*)d_in[1];
    const float* v = (const float*)d_in[2];
    const float* proj = (const float*)d_in[3];
    float* out = (float*)d_out;

    // workspace: kpart 128KB fp32; qpb/kpb 2MB bf16; Gpb 4MB bf16
    float* ws = (float*)d_ws;
    float* kpart = ws;                                           // H*32*M
    unsigned short* qpb = (unsigned short*)(kpart + H * 32 * M); // H*N*M
    unsigned short* kpb = qpb + H * N * M;                       // H*N*M
    unsigned short* Gpb = kpb + H * N * M;                       // H*32*M*D

    k_projg<<<dim3(32, H), 512, 0, stream>>>(q, k, proj, v, qpb, kpb, Gpb,
                                             kpart);
    k_attn<<<dim3(H * NC, 4), 512, 0, stream>>>(qpb, kpb, kpart, Gpb, v, out);
}